// Round 3
// baseline (161.201 us; speedup 1.0000x reference)
//
#include <hip/hip_runtime.h>

#define N_TOT 8192
#define DIMS  512

typedef __attribute__((ext_vector_type(8))) short bf16x8;
typedef __attribute__((ext_vector_type(4))) float f32x4;

static __device__ inline unsigned short f2bf(float f) {
    unsigned u = __float_as_uint(f);
    unsigned r = (u + 0x7fffu + ((u >> 16) & 1u)) >> 16;
    return (unsigned short)r;
}

// Kernel 1: convert to bf16, per-row sum of squares (fp32), column sums via
// fp32 device atomics, total sum-of-squares via one atomic per block.
// 128 blocks x 256 threads, 64 rows/block (16 rows/wave).
__global__ __launch_bounds__(256) void prep_kernel(
    const float* __restrict__ src, const float* __restrict__ tgt,
    unsigned short* __restrict__ Tb, float* __restrict__ sq,
    float* __restrict__ colsum, float* __restrict__ sumsqtot)
{
    __shared__ float cp[4 * 512];
    __shared__ float wss[4];
    int lane = threadIdx.x & 63;
    int wave = threadIdx.x >> 6;
    int b = blockIdx.x;

    float colacc[8];
#pragma unroll
    for (int j = 0; j < 8; j++) colacc[j] = 0.f;
    float wsum = 0.f;

#pragma unroll 4
    for (int rr = 0; rr < 16; rr++) {
        int row = b * 64 + wave * 16 + rr;
        const float* p = (row < 4096) ? (src + (size_t)row * DIMS)
                                      : (tgt + (size_t)(row - 4096) * DIMS);
        float4 v0 = *(const float4*)(p + lane * 8);
        float4 v1 = *(const float4*)(p + lane * 8 + 4);
        float vs[8] = {v0.x, v0.y, v0.z, v0.w, v1.x, v1.y, v1.z, v1.w};
        float rs = 0.f;
        unsigned out[4];
#pragma unroll
        for (int j = 0; j < 8; j++) { rs += vs[j] * vs[j]; colacc[j] += vs[j]; }
#pragma unroll
        for (int j = 0; j < 4; j++)
            out[j] = (unsigned)f2bf(vs[2 * j]) | ((unsigned)f2bf(vs[2 * j + 1]) << 16);
        *(uint4*)(Tb + (size_t)row * DIMS + lane * 8) = make_uint4(out[0], out[1], out[2], out[3]);
#pragma unroll
        for (int off = 32; off; off >>= 1) rs += __shfl_down(rs, off, 64);
        if (lane == 0) { sq[row] = rs; wsum += rs; }
    }
    if (lane == 0) wss[wave] = wsum;
#pragma unroll
    for (int j = 0; j < 8; j++) cp[wave * 512 + lane * 8 + j] = colacc[j];
    __syncthreads();
    int t = threadIdx.x;
    float c0 = cp[t] + cp[512 + t] + cp[1024 + t] + cp[1536 + t];
    float c1 = cp[t + 256] + cp[512 + t + 256] + cp[1024 + t + 256] + cp[1536 + t + 256];
    atomicAdd(&colsum[t], c0);
    atomicAdd(&colsum[t + 256], c1);
    if (t == 0) atomicAdd(sumsqtot, wss[0] + wss[1] + wss[2] + wss[3]);
}

// Kernel 2: bandwidth = (2*N*sum(sq) - 2*||colsum||^2) / (N^2-N) / 4   (fp64)
__global__ __launch_bounds__(512) void bw_kernel(
    const float* __restrict__ colsum, const float* __restrict__ sumsqtot,
    double* __restrict__ bwout)
{
    int t = threadIdx.x;  // 512 threads
    float cs = colsum[t];
    double c2 = (double)cs * (double)cs;
#pragma unroll
    for (int off = 32; off; off >>= 1) c2 += __shfl_down(c2, off, 64);
    __shared__ double rc[8];
    if ((t & 63) == 0) rc[t >> 6] = c2;
    __syncthreads();
    if (t == 0) {
        double C2 = 0.0;
        for (int w = 0; w < 8; w++) C2 += rc[w];
        double SS = (double)sumsqtot[0];
        double suml2 = 2.0 * 8192.0 * SS - 2.0 * C2;
        double denom = 8192.0 * 8192.0 - 8192.0;
        bwout[0] = suml2 / denom / 4.0;  // kernel_mul^(kernel_num//2) = 4
    }
}

// Kernel 3: main fused pairwise-kernel tile. Packed upper-triangle (2080
// blocks, row-major order), 128x128 tile, BK=32, rotated single-barrier
// double-buffered LDS staging, 4 waves (2x2), 4x4 mfma 16x16x32 bf16.
__global__ __launch_bounds__(256) void mmd_main(
    const unsigned short* __restrict__ Tb, const float* __restrict__ sq,
    const double* __restrict__ bwp, double* __restrict__ accum)
{
    int b = blockIdx.x;
    // triangular decode: row I starts at I*(129-I)/2
    int I = (int)((129.0 - sqrt(129.0 * 129.0 - 8.0 * (double)b)) * 0.5);
    while ((I + 1) * (129 - (I + 1)) / 2 <= b) I++;
    while (I * (129 - I) / 2 > b) I--;
    int J = I + (b - I * (129 - I) / 2);

    __shared__ __align__(16) unsigned short As[2][128 * 32];
    __shared__ __align__(16) unsigned short Bs[2][128 * 32];
    __shared__ float sqA[128], sqB[128];
    __shared__ float wsum[4];

    int t = threadIdx.x;
    int lane = t & 63, wave = t >> 6;
    int wr = (wave >> 1) * 64, wc = (wave & 1) * 64;
    int m = lane & 15, quad = lane >> 4;

    if (t < 128) sqA[t] = sq[I * 128 + t];
    else         sqB[t - 128] = sq[J * 128 + (t - 128)];

    double bwv = bwp[0];  // issue early; used only in epilogue

    const unsigned short* Arow = Tb + (size_t)I * 128 * DIMS;
    const unsigned short* Brow = Tb + (size_t)J * 128 * DIMS;
    int ldrow = wave * 16 + (lane >> 2);  // row within 64-row slab
    int ldcol = (lane & 3) * 8;           // 16B granule offset

    // stage tile k0 (elements k0*32 .. +32) into buffer `buf`
    auto issue = [&](int k0, int buf) {
#pragma unroll
        for (int p = 0; p < 2; p++) {
            int r = p * 64 + ldrow;
            const unsigned short* ga = Arow + (size_t)r * DIMS + k0 + ldcol;
            const unsigned short* gb = Brow + (size_t)r * DIMS + k0 + ldcol;
            __builtin_amdgcn_global_load_lds(
                (const __attribute__((address_space(1))) void*)ga,
                (__attribute__((address_space(3))) void*)&As[buf][(p * 64 + wave * 16) * 32], 16, 0, 0);
            __builtin_amdgcn_global_load_lds(
                (const __attribute__((address_space(1))) void*)gb,
                (__attribute__((address_space(3))) void*)&Bs[buf][(p * 64 + wave * 16) * 32], 16, 0, 0);
        }
    };

    f32x4 acc[4][4] = {};
    issue(0, 0);

    for (int k = 0; k < 16; k++) {
        int cur = k & 1;
        // Barrier: (a) drains vmcnt -> buf[cur] (issued one compute-phase ago)
        // is complete; (b) all waves are done reading buf[cur^1] from iter k-1,
        // so it is safe to overwrite it with the prefetch below.
        __syncthreads();
        if (k < 15) issue((k + 1) * 32, cur ^ 1);  // flies during this iter's MFMAs
        bf16x8 af[4], bfr[4];
#pragma unroll
        for (int mi = 0; mi < 4; mi++)
            af[mi] = *(const bf16x8*)&As[cur][(wr + mi * 16 + m) * 32 + quad * 8];
#pragma unroll
        for (int ni = 0; ni < 4; ni++)
            bfr[ni] = *(const bf16x8*)&Bs[cur][(wc + ni * 16 + m) * 32 + quad * 8];
#pragma unroll
        for (int mi = 0; mi < 4; mi++)
#pragma unroll
            for (int ni = 0; ni < 4; ni++)
                acc[mi][ni] = __builtin_amdgcn_mfma_f32_16x16x32_bf16(
                    af[mi], bfr[ni], acc[mi][ni], 0, 0, 0);
    }

    // Epilogue: l2 -> 5-bandwidth Gaussian sum via power chain:
    //   sum_i exp(-t/2^i) = u + u^2 + u^4 + u^8 + u^16,  u = exp(-t/16)
    float c16 = (float)(1.0 / bwv) * 0.0625f;
    float lsum = 0.f;
    bool diag = (I == J);
#pragma unroll
    for (int mi = 0; mi < 4; mi++) {
#pragma unroll
        for (int ni = 0; ni < 4; ni++) {
#pragma unroll
            for (int r = 0; r < 4; r++) {
                float dot = acc[mi][ni][r];
                int rl = wr + mi * 16 + quad * 4 + r;  // C row = A-side index
                int cl = wc + ni * 16 + m;             // C col = B-side index
                float l2 = sqA[rl] + sqB[cl] - 2.0f * dot;
                l2 = fmaxf(l2, 0.f);
                float kv;
                if (diag && rl == cl) {
                    kv = 5.0f;
                } else {
                    float u = __expf(-l2 * c16);
                    float u2 = u * u;
                    float u4 = u2 * u2;
                    float u8 = u4 * u4;
                    float u16 = u8 * u8;
                    kv = ((u + u2) + (u4 + u8)) + u16;
                }
                lsum += kv;
            }
        }
    }
#pragma unroll
    for (int off = 32; off; off >>= 1) lsum += __shfl_down(lsum, off, 64);
    if (lane == 0) wsum[wave] = lsum;
    __syncthreads();
    if (t == 0) {
        double s = (double)wsum[0] + (double)wsum[1] + (double)wsum[2] + (double)wsum[3];
        double wgt = diag ? 1.0 : 2.0;                 // off-diagonal tiles count twice
        bool cross = (I < 32) != (J < 32);             // xy/yx quadrant -> negative sign
        atomicAdd(accum, s * wgt * (cross ? -1.0 : 1.0));
    }
}

// Kernel 4: scale accumulated sum -> scalar result
__global__ void final_kernel(const double* __restrict__ accum, float* __restrict__ out)
{
    if (threadIdx.x == 0)
        out[0] = (float)(accum[0] / (4096.0 * 4096.0));
}

extern "C" void kernel_launch(void* const* d_in, const int* in_sizes, int n_in,
                              void* d_out, int out_size, void* d_ws, size_t ws_size,
                              hipStream_t stream) {
    const float* src = (const float*)d_in[0];
    const float* tgt = (const float*)d_in[1];
    char* ws = (char*)d_ws;
    unsigned short* Tb = (unsigned short*)ws;                  // 8 MiB bf16 [8192][512]
    float* sq          = (float*)(ws + 8u * 1024 * 1024);      // 32 KiB
    char* zblock       = ws + 8u * 1024 * 1024 + 32 * 1024;    // 4 KiB zero-init block
    float* colsum      = (float*)zblock;                       // 2 KiB
    float* sumsqtot    = (float*)(zblock + 2048);              // 4 B
    double* accum      = (double*)(zblock + 2056);             // 8 B (8-aligned)
    double* bw         = (double*)(zblock + 4096);             // 8 B

    hipMemsetAsync(zblock, 0, 4096, stream);
    prep_kernel<<<128, 256, 0, stream>>>(src, tgt, Tb, sq, colsum, sumsqtot);
    bw_kernel<<<1, 512, 0, stream>>>(colsum, sumsqtot, bw);
    mmd_main<<<2080, 256, 0, stream>>>(Tb, sq, bw, accum);
    final_kernel<<<1, 64, 0, stream>>>(accum, (float*)d_out);
}